// Round 4
// baseline (368.207 us; speedup 1.0000x reference)
//
#include <hip/hip_runtime.h>

#define BATCH 4
#define NHEADS 3
#define SEQ 2048
#define HDIM 256
#define EMBD 768
#define MTOT (BATCH*SEQ)          // 8192
#define WSZ (NHEADS*EMBD*HDIM)    // 589824 per projection weight

typedef unsigned short u16x8 __attribute__((ext_vector_type(8)));
typedef unsigned short u16x4 __attribute__((ext_vector_type(4)));
typedef __bf16 bf16x8 __attribute__((ext_vector_type(8)));
typedef float fx4 __attribute__((ext_vector_type(4)));

__device__ __forceinline__ unsigned short f2bf(float x) {
    union { float f; unsigned int u; } v; v.f = x;
    unsigned int r = v.u + 0x7fffu + ((v.u >> 16) & 1u);
    return (unsigned short)(r >> 16);
}

__device__ __forceinline__ fx4 mfma16(u16x8 a, u16x8 b, fx4 c) {
    return __builtin_amdgcn_mfma_f32_16x16x32_bf16(
        __builtin_bit_cast(bf16x8, a), __builtin_bit_cast(bf16x8, b), c, 0, 0, 0);
}

// async global->LDS, 16B per lane. LDS dest must be wave-uniform-base +
// lane*16 contiguous (m97/m104); swizzled layouts via pre-swizzled SOURCE.
__device__ __forceinline__ void gl_lds16(const unsigned short* g, unsigned short* l) {
    __builtin_amdgcn_global_load_lds(
        (const __attribute__((address_space(1))) unsigned int*)g,
        (__attribute__((address_space(3))) unsigned int*)l, 16, 0, 0);
}

// attn schedule: entry = qt128<<4 | (nc-1)<<2 | chunk. 128-row q-tiles.
// qt<=5 direct (nc=1); qt 6..11 split 2-way; qt 12..15 split 3-way.
// Sorted heaviest-chunk-first for scheduling. 30 entries x 12 bh = 360 blocks.
__device__ const unsigned char attn_sched[30] = {
     80,180,181,164,165,250,248,249, 64,148,
    149,232,233,234,217,218,132,133,216,202,
    200,201,116,117, 48,100,101, 32, 16,  0
};

// ---------------------------------------------------------------------------
// Kernel 1: cast A inputs fp32->bf16 + weight cast/transpose. (unchanged)
// ---------------------------------------------------------------------------
__global__ __launch_bounds__(256) void castAw_kernel(
    const float* __restrict__ Ak, const float* __restrict__ Av,
    const float* __restrict__ Aq,
    const float* __restrict__ Wk, const float* __restrict__ Wv,
    const float* __restrict__ Wq, const float* __restrict__ Wo,
    unsigned short* __restrict__ Abf, unsigned short* __restrict__ Wt,
    unsigned short* __restrict__ Wot)
{
    __shared__ float tile[64][65];
    int bx = blockIdx.x;
    if (bx < 9216) {            // A cast: 3 * 8192*768 elems, 8 per thread
        int e = (bx * 256 + threadIdx.x) * 8;
        int t = e / (MTOT * EMBD);
        int r = e - t * (MTOT * EMBD);
        const float* A = (t == 0) ? Ak : (t == 1) ? Av : Aq;
        const fx4* s = (const fx4*)(A + r);
        fx4 v0 = s[0], v1 = s[1];
        u16x8 o;
        o[0]=f2bf(v0[0]); o[1]=f2bf(v0[1]); o[2]=f2bf(v0[2]); o[3]=f2bf(v0[3]);
        o[4]=f2bf(v1[0]); o[5]=f2bf(v1[1]); o[6]=f2bf(v1[2]); o[7]=f2bf(v1[3]);
        *(u16x8*)(Abf + e) = o;
        return;
    }
    int z = bx - 9216;          // weight transpose via 64x64 LDS tile
    const float* src; unsigned short* dst;
    int src_ld, dst_ld, e0, f0;
    if (z < 432) {
        int t = z / 144, rem = z - t * 144;
        int h = rem / 48, tl = rem - h * 48;
        e0 = (tl % 12) * 64; f0 = (tl / 12) * 64;
        const float* W = (t == 0) ? Wk : (t == 1) ? Wv : Wq;
        src = W + h * 768 * 256; src_ld = 256;
        dst = Wt + t * WSZ + h * 256 * 768; dst_ld = 768;
    } else {
        int zz = z - 432;
        e0 = (zz % 12) * 64; f0 = (zz / 12) * 64;
        src = Wo; src_ld = 768;
        dst = Wot; dst_ld = 768;
    }
    int tx = threadIdx.x & 63, ty4 = threadIdx.x >> 6;
    #pragma unroll
    for (int i = 0; i < 16; ++i) {
        int r = ty4 + i * 4;
        tile[r][tx] = src[(e0 + r) * src_ld + f0 + tx];
    }
    __syncthreads();
    #pragma unroll
    for (int i = 0; i < 16; ++i) {
        int r = ty4 + i * 4;
        dst[(f0 + r) * dst_ld + e0 + tx] = f2bf(tile[tx][r]);
    }
}

// ---------------------------------------------------------------------------
// Kernel 2: projection GEMM, m97 structure. (unchanged)
// ---------------------------------------------------------------------------
__global__ __launch_bounds__(256) void proj_kernel(
    const unsigned short* __restrict__ Abf, const unsigned short* __restrict__ Wt,
    unsigned short* __restrict__ Kg, unsigned short* __restrict__ Vg,
    unsigned short* __restrict__ Qg)
{
    __shared__ alignas(16) unsigned short S[17408];
    unsigned short* As = S;
    unsigned short* Bs = S + 8192;

    int z = blockIdx.z;
    const unsigned short* A = Abf + z * (MTOT * EMBD);
    int m0 = blockIdx.x * 128;
    int h = blockIdx.y >> 1, fbase = (blockIdx.y & 1) * 128;
    const unsigned short* W = Wt + z * WSZ + (h * 256 + fbase) * EMBD;

    int tid = threadIdx.x;
    int w = tid >> 6, ln = tid & 63;
    int lane16 = ln & 15, quad = ln >> 4;
    int mw = (w & 1) * 64, nw = (w >> 1) * 64;

    fx4 acc[4][4];
    #pragma unroll
    for (int i = 0; i < 4; ++i)
        #pragma unroll
        for (int j = 0; j < 4; ++j) acc[i][j] = (fx4){0.f, 0.f, 0.f, 0.f};

    int c0 = tid, c1 = tid + 256;
    int r0 = c0 >> 2, s0_ = (c0 & 3) * 8;
    int r1 = c1 >> 2, s1_ = (c1 & 3) * 8;
    const unsigned short* Ag0 = A + (m0 + r0) * EMBD + s0_;
    const unsigned short* Ag1 = A + (m0 + r1) * EMBD + s1_;
    const unsigned short* Wg0 = W + r0 * EMBD + s0_;
    const unsigned short* Wg1 = W + r1 * EMBD + s1_;

    for (int kb = 0; kb < EMBD; kb += 32) {
        __syncthreads();
        gl_lds16(Ag0 + kb, &As[c0 * 8]);
        gl_lds16(Ag1 + kb, &As[c1 * 8]);
        gl_lds16(Wg0 + kb, &Bs[c0 * 8]);
        gl_lds16(Wg1 + kb, &Bs[c1 * 8]);
        __syncthreads();

        u16x8 af[4], bf[4];
        #pragma unroll
        for (int i = 0; i < 4; ++i) {
            af[i] = *(const u16x8*)&As[(mw + i * 16 + lane16) * 32 + quad * 8];
            bf[i] = *(const u16x8*)&Bs[(nw + i * 16 + lane16) * 32 + quad * 8];
        }
        #pragma unroll
        for (int i = 0; i < 4; ++i)
            #pragma unroll
            for (int j = 0; j < 4; ++j)
                acc[i][j] = mfma16(af[i], bf[j], acc[i][j]);
    }

    __syncthreads();
    int b = m0 >> 11, sq0 = m0 & 2047;

    if (z == 1) {
        #pragma unroll
        for (int i = 0; i < 4; ++i)
            #pragma unroll
            for (int j = 0; j < 4; ++j) {
                int fl = nw + j * 16 + lane16;
                int ml = mw + i * 16 + quad * 4;
                u16x4 pk;
                pk[0] = f2bf(acc[i][j][0]); pk[1] = f2bf(acc[i][j][1]);
                pk[2] = f2bf(acc[i][j][2]); pk[3] = f2bf(acc[i][j][3]);
                *(u16x4*)&S[fl * 136 + ml] = pk;
            }
        __syncthreads();
        int fl = tid >> 1, mseg = (tid & 1) * 64;
        const unsigned short* srcp = &S[fl * 136 + mseg];
        unsigned short* dstp = Vg + ((b * NHEADS + h) * HDIM + fbase + fl) * SEQ + sq0 + mseg;
        #pragma unroll
        for (int c = 0; c < 8; ++c)
            *(u16x8*)(dstp + c * 8) = *(const u16x8*)(srcp + c * 8);
    } else {
        #pragma unroll
        for (int i = 0; i < 4; ++i)
            #pragma unroll
            for (int j = 0; j < 4; ++j) {
                int fl = nw + j * 16 + lane16;
                int ml = mw + i * 16 + quad * 4;
                #pragma unroll
                for (int r = 0; r < 4; ++r)
                    S[(ml + r) * 136 + fl] = f2bf(acc[i][j][r]);
            }
        __syncthreads();
        unsigned short* dst0 = (z == 0) ? Kg : Qg;
        int ml = tid >> 1, fseg = (tid & 1) * 64;
        const unsigned short* srcp = &S[ml * 136 + fseg];
        unsigned short* dstp = dst0 + ((b * NHEADS + h) * SEQ + sq0 + ml) * HDIM + fbase + fseg;
        #pragma unroll
        for (int c = 0; c < 8; ++c)
            *(u16x8*)(dstp + c * 8) = *(const u16x8*)(srcp + c * 8);
    }
}

// ---------------------------------------------------------------------------
// Kernel 3: causal attention. Block = 4 waves x 32 q-rows (128-row q-tile):
// K/V frags reused across 2 q-groups -> 2.5x less LDS read traffic per unit
// work. 32-key tiles, double-buffered, staged via global_load_lds DMA (no
// ds_writes — the old kernel's 1.3e7 bank conflicts were 8-way staging-write
// conflicts). Conflict-free LDS via XOR swizzle applied on the pre-swizzled
// GLOBAL source (rule #21):
//   K: chunk16 j stored at j^(row&7)   (row stride 512B)
//   V: chunk (f,q) stored at slot q*8+(f&7) within 8-f-row group of 512B
// Packed-bf16 shfl P-transform (8 shfl/group vs 16). One barrier per tile.
// ---------------------------------------------------------------------------
__global__ __launch_bounds__(256, 2) void attn_kernel(
    const unsigned short* __restrict__ Kg, const unsigned short* __restrict__ Vg,
    const unsigned short* __restrict__ Qg, unsigned short* __restrict__ heads,
    float* __restrict__ Opart, float* __restrict__ Lpart)
{
    __shared__ alignas(16) unsigned short Kbuf[2 * 32 * 256];  // 32 KB
    __shared__ alignas(16) unsigned short Vbuf[2 * 256 * 32];  // 32 KB

    int bx = blockIdx.x;
    int bh = bx % 12;
    int ent = attn_sched[bx / 12];
    int qt = ent >> 4, nc = ((ent >> 2) & 3) + 1, ck = ent & 3;
    int tid = threadIdx.x;
    int w = tid >> 6, ln = tid & 63;
    int lane16 = ln & 15, quad = ln >> 4;
    int q0w = qt * 128 + w * 32;

    const unsigned short* Kbase = Kg + bh * (SEQ * HDIM);
    const unsigned short* Vbase = Vg + bh * (SEQ * HDIM);  // [f][s]
    const unsigned short* Qbase = Qg + bh * (SEQ * HDIM);

    // Q fragments for both 16-row groups (rows q0w+lane16, q0w+16+lane16)
    u16x8 qf0[8], qf1[8];
    {
        const unsigned short* qr = Qbase + (q0w + lane16) * HDIM + quad * 8;
        #pragma unroll
        for (int c = 0; c < 8; ++c) {
            qf0[c] = *(const u16x8*)(qr + c * 32);
            qf1[c] = *(const u16x8*)(qr + 16 * HDIM + c * 32);
        }
    }

    fx4 o0[16], o1[16];
    #pragma unroll
    for (int i = 0; i < 16; ++i) {
        o0[i] = (fx4){0.f, 0.f, 0.f, 0.f};
        o1[i] = (fx4){0.f, 0.f, 0.f, 0.f};
    }
    float ls0 = 0.f, ls1 = 0.f;

    const float Cs2 = 0.03188010519640429f;  // log2(e)/sqrt(2048)

    int n32 = 4 * (qt + 1);
    int t0 = (ck * n32) / nc, t1 = ((ck + 1) * n32) / nc;

    // staging source offsets (inverse-swizzled global addresses)
    int koff[4], voff[4];
    #pragma unroll
    for (int i = 0; i < 4; ++i) {
        int d = i * 256 + tid;          // dest 16B-chunk index in 16KB tile
        int r = d >> 5, j = d & 31;
        koff[i] = r * HDIM + ((j ^ (r & 7)) * 8);          // K row r, chunk j
        voff[i] = (r * 8 + (j & 7)) * SEQ + (j >> 3) * 8;  // V f=r*8+(j&7), kq=j>>3
    }

    int sw8 = (lane16 & 7) * 8;

#define STAGE(buf_, kt_) do {                                                  \
        int k0s = (kt_) * 32;                                                  \
        unsigned short* kd = Kbuf + (buf_) * (32 * 256);                       \
        unsigned short* vd = Vbuf + (buf_) * (256 * 32);                       \
        _Pragma("unroll")                                                      \
        for (int i_ = 0; i_ < 4; ++i_)                                         \
            gl_lds16(Kbase + koff[i_] + k0s * HDIM, kd + (i_ * 256 + tid) * 8);\
        _Pragma("unroll")                                                      \
        for (int i_ = 0; i_ < 4; ++i_)                                         \
            gl_lds16(Vbase + voff[i_] + k0s, vd + (i_ * 256 + tid) * 8);       \
    } while (0)

    STAGE(0, t0);
    int cur = 0;

    for (int kt = t0; kt < t1; ++kt) {
        __syncthreads();               // vmcnt(0) drain: tile kt landed; prev buf free
        if (kt + 1 < t1) STAGE(cur ^ 1, kt + 1);   // overlaps this tile's compute

        const unsigned short* KB = Kbuf + cur * (32 * 256);
        const unsigned short* VB = Vbuf + cur * (256 * 32);

        // QK^T: S^T[key][q], keys 0-15 (A) and 16-31 (B), both q-groups.
        fx4 sA0 = (fx4){0.f,0.f,0.f,0.f}, sB0 = (fx4){0.f,0.f,0.f,0.f};
        fx4 sA1 = (fx4){0.f,0.f,0.f,0.f}, sB1 = (fx4){0.f,0.f,0.f,0.f};
        __builtin_amdgcn_s_setprio(1);
        #pragma unroll
        for (int c = 0; c < 8; ++c) {
            int col = ((c * 4 + quad) ^ (lane16 & 7)) * 8;
            u16x8 kA = *(const u16x8*)&KB[lane16 * 256 + col];
            u16x8 kB = *(const u16x8*)&KB[(16 + lane16) * 256 + col];
            sA0 = mfma16(kA, qf0[c], sA0);
            sB0 = mfma16(kB, qf0[c], sB0);
            sA1 = mfma16(kA, qf1[c], sA1);
            sB1 = mfma16(kB, qf1[c], sB1);
        }
        __builtin_amdgcn_s_setprio(0);

        int k0 = kt * 32;
        u16x8 pf0, pf1;
        {   // group 0: q = q0w + lane16
            int q = q0w + lane16;
            unsigned int pp[4];
            #pragma unroll
            for (int r = 0; r < 4; ++r) {
                int ka_ = k0 + quad * 4 + r;
                float e0 = exp2f(sA0[r] * Cs2);
                float e1 = exp2f(sB0[r] * Cs2);
                float v0 = (ka_      <= q) ? e0 : 0.f;
                float v1 = (ka_ + 16 <= q) ? e1 : 0.f;
                ls0 += v0 + v1;
                pp[r] = (unsigned int)f2bf(v0) | ((unsigned int)f2bf(v1) << 16);
            }
            #pragma unroll
            for (int j = 0; j < 8; ++j) {
                int srcLane = ((((quad << 1) + (j >> 2)) & 3) << 4) | lane16;
                unsigned int ts = (unsigned int)__shfl((int)pp[j & 3], srcLane, 64);
                pf0[j] = (quad >= 2) ? (unsigned short)(ts >> 16) : (unsigned short)ts;
            }
        }
        {   // group 1: q = q0w + 16 + lane16
            int q = q0w + 16 + lane16;
            unsigned int pp[4];
            #pragma unroll
            for (int r = 0; r < 4; ++r) {
                int ka_ = k0 + quad * 4 + r;
                float e0 = exp2f(sA1[r] * Cs2);
                float e1 = exp2f(sB1[r] * Cs2);
                float v0 = (ka_      <= q) ? e0 : 0.f;
                float v1 = (ka_ + 16 <= q) ? e1 : 0.f;
                ls1 += v0 + v1;
                pp[r] = (unsigned int)f2bf(v0) | ((unsigned int)f2bf(v1) << 16);
            }
            #pragma unroll
            for (int j = 0; j < 8; ++j) {
                int srcLane = ((((quad << 1) + (j >> 2)) & 3) << 4) | lane16;
                unsigned int ts = (unsigned int)__shfl((int)pp[j & 3], srcLane, 64);
                pf1[j] = (quad >= 2) ? (unsigned short)(ts >> 16) : (unsigned short)ts;
            }
        }

        // PV: V frags read once, used by both q-groups.
        __builtin_amdgcn_s_setprio(1);
        #pragma unroll
        for (int ft = 0; ft < 16; ++ft) {
            u16x8 vf = *(const u16x8*)&VB[(ft * 2 + (lane16 >> 3)) * 256 + quad * 64 + sw8];
            o0[ft] = mfma16(pf0, vf, o0[ft]);
            o1[ft] = mfma16(pf1, vf, o1[ft]);
        }
        __builtin_amdgcn_s_setprio(0);
        cur ^= 1;
    }
#undef STAGE

    ls0 += __shfl_xor(ls0, 16, 64);
    ls0 += __shfl_xor(ls0, 32, 64);
    ls1 += __shfl_xor(ls1, 16, 64);
    ls1 += __shfl_xor(ls1, 32, 64);

    int b = bh / 3, h = bh - (bh / 3) * 3;

    if (nc == 1) {
        float li0 = 1.f / ls0, li1 = 1.f / ls1;
        float inv0[4], inv1[4];
        #pragma unroll
        for (int r = 0; r < 4; ++r) {
            inv0[r] = __shfl(li0, quad * 4 + r, 64);
            inv1[r] = __shfl(li1, quad * 4 + r, 64);
        }
        unsigned short* hp0 = heads + (b * SEQ + q0w + quad * 4) * EMBD + h * HDIM + lane16;
        unsigned short* hp1 = hp0 + 16 * EMBD;
        #pragma unroll
        for (int ft = 0; ft < 16; ++ft)
            #pragma unroll
            for (int r = 0; r < 4; ++r) {
                hp0[r * EMBD + ft * 16] = f2bf(o0[ft][r] * inv0[r]);
                hp1[r * EMBD + ft * 16] = f2bf(o1[ft][r] * inv1[r]);
            }
    } else {
        int local = (qt < 12) ? (qt - 6) * 2 : (12 + (qt - 12) * 3);
        int slot = bh * 24 + local + ck;
        float* Op = Opart + slot * 32768 + (w * 32 + quad * 4) * 256 + lane16;
        #pragma unroll
        for (int ft = 0; ft < 16; ++ft)
            #pragma unroll
            for (int r = 0; r < 4; ++r) {
                Op[r * 256 + ft * 16] = o0[ft][r];
                Op[16 * 256 + r * 256 + ft * 16] = o1[ft][r];
            }
        if (quad == 0) {
            Lpart[slot * 128 + w * 32 + lane16] = ls0;
            Lpart[slot * 128 + w * 32 + 16 + lane16] = ls1;
        }
    }
}

// ---------------------------------------------------------------------------
// Kernel 4: combine split-k partials (qt 6..15), normalize, write heads bf16.
// ---------------------------------------------------------------------------
__global__ __launch_bounds__(256) void combine_kernel(
    const float* __restrict__ Opart, const float* __restrict__ Lpart,
    unsigned short* __restrict__ heads)
{
    int t = blockIdx.x;              // 120: bh*10 + (qt-6)
    int bh = t / 10, qt = (t - bh * 10) + 6;
    int nc = (qt < 12) ? 2 : 3;
    int local = (qt < 12) ? (qt - 6) * 2 : (12 + (qt - 12) * 3);
    int sbase = bh * 24 + local;
    int tid = threadIdx.x;
    int row = tid >> 1, fseg = (tid & 1) * 128;
    float l = Lpart[(sbase + 0) * 128 + row] + Lpart[(sbase + 1) * 128 + row];
    if (nc == 3) l += Lpart[(sbase + 2) * 128 + row];
    float inv = 1.f / l;
    const fx4* O0 = (const fx4*)(Opart + (sbase + 0) * 32768 + row * 256 + fseg);
    const fx4* O1 = (const fx4*)(Opart + (sbase + 1) * 32768 + row * 256 + fseg);
    const fx4* O2 = (const fx4*)(Opart + (sbase + 2) * 32768 + row * 256 + fseg);
    int b = bh / 3, h = bh - (bh / 3) * 3;
    unsigned short* hp = heads + (b * SEQ + qt * 128 + row) * EMBD + h * HDIM + fseg;
    #pragma unroll
    for (int i = 0; i < 32; ++i) {
        fx4 v = O0[i] + O1[i];
        if (nc == 3) v = v + O2[i];
        u16x4 pk;
        pk[0] = f2bf(v[0] * inv); pk[1] = f2bf(v[1] * inv);
        pk[2] = f2bf(v[2] * inv); pk[3] = f2bf(v[3] * inv);
        *(u16x4*)(hp + i * 4) = pk;
    }
}

// ---------------------------------------------------------------------------
// Kernel 5: output projection, m97 structure. (unchanged)
// ---------------------------------------------------------------------------
__global__ __launch_bounds__(256) void outproj_kernel(
    const unsigned short* __restrict__ A, const unsigned short* __restrict__ Wot,
    const float* __restrict__ bo, float* __restrict__ out)
{
    __shared__ alignas(16) unsigned short S[16384];
    unsigned short* As = S;
    unsigned short* Bs = S + 8192;

    int m0 = blockIdx.x * 128, n0 = blockIdx.y * 128;
    int tid = threadIdx.x;
    int w = tid >> 6, ln = tid & 63;
    int lane16 = ln & 15, quad = ln >> 4;
    int mw = (w & 1) * 64, nw = (w >> 1) * 64;

    fx4 acc[4][4];
    #pragma unroll
    for (int i = 0; i < 4; ++i)
        #pragma unroll
        for (int j = 0; j < 4; ++j) acc[i][j] = (fx4){0.f, 0.f, 0.f, 0.f};

    int c0 = tid, c1 = tid + 256;
    int r0 = c0 >> 2, s0_ = (c0 & 3) * 8;
    int r1 = c1 >> 2, s1_ = (c1 & 3) * 8;
    const unsigned short* Ag0 = A + (m0 + r0) * EMBD + s0_;
    const unsigned short* Ag1 = A + (m0 + r1) * EMBD + s1_;
    const unsigned short* Wg0 = Wot + (n0 + r0) * EMBD + s0_;
    const unsigned short* Wg1 = Wot + (n0 + r1) * EMBD + s1_;

    for (int kb = 0; kb < EMBD; kb += 32) {
        __syncthreads();
        gl_lds16(Ag0 + kb, &As[c0 * 8]);
        gl_lds16(Ag1 + kb, &As[c1 * 8]);
        gl_lds16(Wg0 + kb, &Bs[c0 * 8]);
        gl_lds16(Wg1 + kb, &Bs[c1 * 8]);
        __syncthreads();

        u16x8 af[4], bf[4];
        #pragma unroll
        for (int i = 0; i < 4; ++i) {
            af[i] = *(const u16x8*)&As[(mw + i * 16 + lane16) * 32 + quad * 8];
            bf[i] = *(const u16x8*)&Bs[(nw + i * 16 + lane16) * 32 + quad * 8];
        }
        #pragma unroll
        for (int i = 0; i < 4; ++i)
            #pragma unroll
            for (int j = 0; j < 4; ++j)
                acc[i][j] = mfma16(af[i], bf[j], acc[i][j]);
    }

    #pragma unroll
    for (int i = 0; i < 4; ++i) {
        int mb = m0 + mw + i * 16 + quad * 4;
        #pragma unroll
        for (int j = 0; j < 4; ++j) {
            int n = n0 + nw + j * 16 + lane16;
            float bias = bo[n];
            #pragma unroll
            for (int r = 0; r < 4; ++r)
                out[(mb + r) * EMBD + n] = acc[i][j][r] + bias;
        }
    }
}

// ---------------------------------------------------------------------------
extern "C" void kernel_launch(void* const* d_in, const int* in_sizes, int n_in,
                              void* d_out, int out_size, void* d_ws, size_t ws_size,
                              hipStream_t stream) {
    const float* Ak = (const float*)d_in[0];
    const float* Av = (const float*)d_in[1];
    const float* Aq = (const float*)d_in[2];
    const float* Wk = (const float*)d_in[3];
    const float* Wv = (const float*)d_in[4];
    const float* Wq = (const float*)d_in[5];
    const float* Wo = (const float*)d_in[6];
    const float* bo = (const float*)d_in[7];
    float* out = (float*)d_out;

    char* base = (char*)d_ws;
    unsigned short* Wt    = (unsigned short*)(base);               // 3.54 MB
    unsigned short* Wot   = (unsigned short*)(base + 3538944);     // 1.18 MB
    unsigned short* Abf   = (unsigned short*)(base + 4718592);     // 37.75 MB
    unsigned short* Kg    = (unsigned short*)(base + 42467328);    // 12.58 MB
    unsigned short* Vg    = (unsigned short*)(base + 55050240);    // 12.58 MB
    unsigned short* Qg    = (unsigned short*)(base + 67633152);    // 12.58 MB
    unsigned short* heads = (unsigned short*)(base + 80216064);    // 12.58 MB
    // split-k partials: Opart overlays Abf (dead after proj), exactly 37.75MB
    // (288 slots x 128 rows x 256 f x fp32); Lpart overlays Wt (dead after proj).
    float* Opart = (float*)(base + 4718592);
    float* Lpart = (float*)(base);

    castAw_kernel<<<dim3(9792), dim3(256), 0, stream>>>(
        Ak, Av, Aq, Wk, Wv, Wq, Wo, Abf, Wt, Wot);
    proj_kernel<<<dim3(64, 6, 3), dim3(256), 0, stream>>>(
        Abf, Wt, Kg, Vg, Qg);
    attn_kernel<<<dim3(360), dim3(256), 0, stream>>>(
        Kg, Vg, Qg, heads, Opart, Lpart);
    combine_kernel<<<dim3(120), dim3(256), 0, stream>>>(Opart, Lpart, heads);
    outproj_kernel<<<dim3(64, 6), dim3(256), 0, stream>>>(heads, Wot, bo, out);
}

// Round 5
// 279.436 us; speedup vs baseline: 1.3177x; 1.3177x over previous
//
#include <hip/hip_runtime.h>

#define BATCH 4
#define NHEADS 3
#define SEQ 2048
#define HDIM 256
#define EMBD 768
#define MTOT (BATCH*SEQ)          // 8192
#define WSZ (NHEADS*EMBD*HDIM)    // 589824 per projection weight

typedef unsigned short u16x8 __attribute__((ext_vector_type(8)));
typedef unsigned short u16x4 __attribute__((ext_vector_type(4)));
typedef __bf16 bf16x8 __attribute__((ext_vector_type(8)));
typedef float fx4 __attribute__((ext_vector_type(4)));

__device__ __forceinline__ unsigned short f2bf(float x) {
    union { float f; unsigned int u; } v; v.f = x;
    unsigned int r = v.u + 0x7fffu + ((v.u >> 16) & 1u);
    return (unsigned short)(r >> 16);
}

__device__ __forceinline__ fx4 mfma16(u16x8 a, u16x8 b, fx4 c) {
    return __builtin_amdgcn_mfma_f32_16x16x32_bf16(
        __builtin_bit_cast(bf16x8, a), __builtin_bit_cast(bf16x8, b), c, 0, 0, 0);
}

// async global->LDS, 16B per lane. LDS dest must be wave-uniform-base +
// lane*16 contiguous (m97/m104 constraint) — callers pass &lds[t*8shorts].
__device__ __forceinline__ void gl_lds16(const unsigned short* g, unsigned short* l) {
    __builtin_amdgcn_global_load_lds(
        (const __attribute__((address_space(1))) unsigned int*)g,
        (__attribute__((address_space(3))) unsigned int*)l, 16, 0, 0);
}

// attn work schedule per (b,h): entries qt*4+kc, kc in {0,1}=k-chunk (qt>=16,
// writes partials), kc=3 = whole causal range (qt<16, writes heads directly).
// (exact baseline schedule — 48 entries x 12 bh = 576 blocks)
__device__ const unsigned char attn_sched[48] = {
    124,125, 63, 120,121, 116,117, 59, 112,113, 108,109, 55, 104,105,
    100,101, 51,  96, 97,  92, 93, 47,  88, 89,  84, 85, 43,  80, 81,
     76, 77, 39,  72, 73,  68, 69, 35,  64, 65,  31, 27, 23, 19, 15,
     11,  7,  3
};

// ---------------------------------------------------------------------------
// Kernel 1: cast A inputs fp32->bf16 + weight cast/transpose. (unchanged)
// ---------------------------------------------------------------------------
__global__ __launch_bounds__(256) void castAw_kernel(
    const float* __restrict__ Ak, const float* __restrict__ Av,
    const float* __restrict__ Aq,
    const float* __restrict__ Wk, const float* __restrict__ Wv,
    const float* __restrict__ Wq, const float* __restrict__ Wo,
    unsigned short* __restrict__ Abf, unsigned short* __restrict__ Wt,
    unsigned short* __restrict__ Wot)
{
    __shared__ float tile[64][65];
    int bx = blockIdx.x;
    if (bx < 9216) {            // A cast: 3 * 8192*768 elems, 8 per thread
        int e = (bx * 256 + threadIdx.x) * 8;
        int t = e / (MTOT * EMBD);
        int r = e - t * (MTOT * EMBD);
        const float* A = (t == 0) ? Ak : (t == 1) ? Av : Aq;
        const fx4* s = (const fx4*)(A + r);
        fx4 v0 = s[0], v1 = s[1];
        u16x8 o;
        o[0]=f2bf(v0[0]); o[1]=f2bf(v0[1]); o[2]=f2bf(v0[2]); o[3]=f2bf(v0[3]);
        o[4]=f2bf(v1[0]); o[5]=f2bf(v1[1]); o[6]=f2bf(v1[2]); o[7]=f2bf(v1[3]);
        *(u16x8*)(Abf + e) = o;
        return;
    }
    int z = bx - 9216;          // weight transpose via 64x64 LDS tile
    const float* src; unsigned short* dst;
    int src_ld, dst_ld, e0, f0;
    if (z < 432) {
        int t = z / 144, rem = z - t * 144;
        int h = rem / 48, tl = rem - h * 48;
        e0 = (tl % 12) * 64; f0 = (tl / 12) * 64;
        const float* W = (t == 0) ? Wk : (t == 1) ? Wv : Wq;
        src = W + h * 768 * 256; src_ld = 256;
        dst = Wt + t * WSZ + h * 256 * 768; dst_ld = 768;
    } else {
        int zz = z - 432;
        e0 = (zz % 12) * 64; f0 = (zz / 12) * 64;
        src = Wo; src_ld = 768;
        dst = Wot; dst_ld = 768;
    }
    int tx = threadIdx.x & 63, ty4 = threadIdx.x >> 6;
    #pragma unroll
    for (int i = 0; i < 16; ++i) {
        int r = ty4 + i * 4;
        tile[r][tx] = src[(e0 + r) * src_ld + f0 + tx];
    }
    __syncthreads();
    #pragma unroll
    for (int i = 0; i < 16; ++i) {
        int r = ty4 + i * 4;
        dst[(f0 + r) * dst_ld + e0 + tx] = f2bf(tile[tx][r]);
    }
}

// ---------------------------------------------------------------------------
// Kernel 2: projection GEMM — CHANGED this round: BK=64 (12 staging phases
// instead of 24, halves barrier drains; 32 MFMA/phase; 8 gl_lds in flight).
// [128][64] LDS would be 16-way-conflicted (row stride == 0 mod 32 banks);
// fixed by XOR chunk swizzle: chunk s of row r stored at slot s^(r&7), via
// pre-swizzled SOURCE address (linear DMA dest, rule #21). Frag read col =
// ((quad+4*kh)^(lane16&7))*8 -> 8 distinct bank-quads per phase (2-way, free).
// Epilogue via LDS round-trip unchanged; V written transposed.
// ---------------------------------------------------------------------------
__global__ __launch_bounds__(256) void proj_kernel(
    const unsigned short* __restrict__ Abf, const unsigned short* __restrict__ Wt,
    unsigned short* __restrict__ Kg, unsigned short* __restrict__ Vg,
    unsigned short* __restrict__ Qg)
{
    // staging: As = S[0..8191] ([128][64] shorts swizzled), Bs = S[8192..16383]
    // epilogue reuses S as [128][136] (34816B)
    __shared__ alignas(16) unsigned short S[17408];
    unsigned short* As = S;
    unsigned short* Bs = S + 8192;

    int z = blockIdx.z;
    const unsigned short* A = Abf + z * (MTOT * EMBD);
    int m0 = blockIdx.x * 128;
    int h = blockIdx.y >> 1, fbase = (blockIdx.y & 1) * 128;
    const unsigned short* W = Wt + z * WSZ + (h * 256 + fbase) * EMBD;

    int tid = threadIdx.x;
    int w = tid >> 6, ln = tid & 63;
    int lane16 = ln & 15, quad = ln >> 4;
    int mw = (w & 1) * 64, nw = (w >> 1) * 64;

    fx4 acc[4][4];
    #pragma unroll
    for (int i = 0; i < 4; ++i)
        #pragma unroll
        for (int j = 0; j < 4; ++j) acc[i][j] = (fx4){0.f, 0.f, 0.f, 0.f};

    // staging: 1024 16B-chunks per matrix, 4 per thread.
    // dest chunk c -> LDS row R=c>>3, slot c&7; source supplies chunk (c&7)^(R&7)
    const unsigned short *Ag[4], *Wg[4];
    #pragma unroll
    for (int i = 0; i < 4; ++i) {
        int c = tid + 256 * i;
        int R = c >> 3;
        int So = (((c & 7) ^ (R & 7)) * 8);
        Ag[i] = A + (m0 + R) * EMBD + So;
        Wg[i] = W + R * EMBD + So;
    }

    // swizzled frag col offsets for k-subtiles kh=0,1
    int ca0 = ((quad + 0) ^ (lane16 & 7)) * 8;
    int ca1 = ((quad + 4) ^ (lane16 & 7)) * 8;

    for (int kb = 0; kb < EMBD; kb += 64) {
        __syncthreads();                 // prior frag reads complete
        #pragma unroll
        for (int i = 0; i < 4; ++i) {
            gl_lds16(Ag[i] + kb, &As[(tid + 256 * i) * 8]);
            gl_lds16(Wg[i] + kb, &Bs[(tid + 256 * i) * 8]);
        }
        __syncthreads();                 // staging landed (vmcnt drain)

        #pragma unroll
        for (int kh = 0; kh < 2; ++kh) {
            int co = kh ? ca1 : ca0;
            u16x8 af[4], bf[4];
            #pragma unroll
            for (int i = 0; i < 4; ++i) {
                af[i] = *(const u16x8*)&As[(mw + i * 16 + lane16) * 64 + co];
                bf[i] = *(const u16x8*)&Bs[(nw + i * 16 + lane16) * 64 + co];
            }
            #pragma unroll
            for (int i = 0; i < 4; ++i)
                #pragma unroll
                for (int j = 0; j < 4; ++j)
                    acc[i][j] = mfma16(af[i], bf[j], acc[i][j]);
        }
    }

    __syncthreads();                     // all frag reads done; reuse S
    int b = m0 >> 11, sq0 = m0 & 2047;

    if (z == 1) {
        // V: store LDS transposed [f][m] (pad 136), then coalesced [f][s]
        #pragma unroll
        for (int i = 0; i < 4; ++i)
            #pragma unroll
            for (int j = 0; j < 4; ++j) {
                int fl = nw + j * 16 + lane16;
                int ml = mw + i * 16 + quad * 4;
                u16x4 pk;
                pk[0] = f2bf(acc[i][j][0]); pk[1] = f2bf(acc[i][j][1]);
                pk[2] = f2bf(acc[i][j][2]); pk[3] = f2bf(acc[i][j][3]);
                *(u16x4*)&S[fl * 136 + ml] = pk;
            }
        __syncthreads();
        int fl = tid >> 1, mseg = (tid & 1) * 64;
        const unsigned short* srcp = &S[fl * 136 + mseg];
        unsigned short* dstp = Vg + ((b * NHEADS + h) * HDIM + fbase + fl) * SEQ + sq0 + mseg;
        #pragma unroll
        for (int c = 0; c < 8; ++c)
            *(u16x8*)(dstp + c * 8) = *(const u16x8*)(srcp + c * 8);
    } else {
        // K/Q: LDS [m][f] (pad 136), then coalesced [s][f]
        #pragma unroll
        for (int i = 0; i < 4; ++i)
            #pragma unroll
            for (int j = 0; j < 4; ++j) {
                int fl = nw + j * 16 + lane16;
                int ml = mw + i * 16 + quad * 4;
                #pragma unroll
                for (int r = 0; r < 4; ++r)
                    S[(ml + r) * 136 + fl] = f2bf(acc[i][j][r]);
            }
        __syncthreads();
        unsigned short* dst0 = (z == 0) ? Kg : Qg;
        int ml = tid >> 1, fseg = (tid & 1) * 64;
        const unsigned short* srcp = &S[ml * 136 + fseg];
        unsigned short* dstp = dst0 + ((b * NHEADS + h) * SEQ + sq0 + ml) * HDIM + fbase + fseg;
        #pragma unroll
        for (int c = 0; c < 8; ++c)
            *(u16x8*)(dstp + c * 8) = *(const u16x8*)(srcp + c * 8);
    }
}

// ---------------------------------------------------------------------------
// Kernel 3: causal attention — EXACT baseline revert (the ~292.8us config).
// Block = 4 waves x 16 q-rows, K/V 32-key tiles in LDS, register prefetch,
// no-max softmax, shfl P-transform, split-k for qt>=16 with fp32 partials.
// ---------------------------------------------------------------------------
__global__ __launch_bounds__(256) void attn_kernel(
    const unsigned short* __restrict__ Kg, const unsigned short* __restrict__ Vg,
    const unsigned short* __restrict__ Qg, unsigned short* __restrict__ heads,
    float* __restrict__ Opart, float* __restrict__ Lpart)
{
    __shared__ alignas(16) unsigned short Ks[32 * 264];
    __shared__ alignas(16) unsigned short Vs[256 * 40];

    int bx = blockIdx.x;
    int bh = bx % 12;
    int ent = attn_sched[bx / 12];
    int qt = ent >> 2, kc = ent & 3;
    int tid = threadIdx.x;
    int w = tid >> 6, ln = tid & 63;
    int lane16 = ln & 15, quad = ln >> 4;
    int q0w = qt * 64 + w * 16;

    const unsigned short* Kbase = Kg + bh * (SEQ * HDIM);
    const unsigned short* Vbase = Vg + bh * (SEQ * HDIM);  // [f][s]
    const unsigned short* Qbase = Qg + bh * (SEQ * HDIM);

    u16x8 qf[8];
    {
        const unsigned short* qrow = Qbase + (q0w + lane16) * HDIM + quad * 8;
        #pragma unroll
        for (int c = 0; c < 8; ++c) qf[c] = *(const u16x8*)(qrow + c * 32);
    }

    fx4 o[16];
    #pragma unroll
    for (int i = 0; i < 16; ++i) o[i] = (fx4){0.f, 0.f, 0.f, 0.f};
    float lsum = 0.f;

    const float Cs2 = 0.03188010519640429f;  // log2(e)/sqrt(2048)

    int t0, t1;
    if (kc == 3) { t0 = 0; t1 = 2 * qt + 2; }
    else         { t0 = kc * (qt + 1); t1 = t0 + qt + 1; }

    int ksrow = tid >> 3, kseg = tid & 7;
    const unsigned short* kstage = Kbase + ksrow * HDIM + kseg * 32;
    const unsigned short* vstage = Vbase + tid * SEQ;

    u16x8 kreg[4], vreg[4];
    {
        int k0 = t0 * 32;
        #pragma unroll
        for (int j = 0; j < 4; ++j) {
            kreg[j] = *(const u16x8*)(kstage + k0 * HDIM + j * 8);
            vreg[j] = *(const u16x8*)(vstage + k0 + j * 8);
        }
    }

    for (int kt = t0; kt < t1; ++kt) {
        __syncthreads();
        {
            u16x8* kd = (u16x8*)&Ks[ksrow * 264 + kseg * 32];
            kd[0] = kreg[0]; kd[1] = kreg[1]; kd[2] = kreg[2]; kd[3] = kreg[3];
            u16x8* vd = (u16x8*)&Vs[tid * 40];
            vd[0] = vreg[0]; vd[1] = vreg[1]; vd[2] = vreg[2]; vd[3] = vreg[3];
        }
        if (kt + 1 < t1) {
            int k0n = (kt + 1) * 32;
            #pragma unroll
            for (int j = 0; j < 4; ++j) {
                kreg[j] = *(const u16x8*)(kstage + k0n * HDIM + j * 8);
                vreg[j] = *(const u16x8*)(vstage + k0n + j * 8);
            }
        }
        __syncthreads();

        int k0 = kt * 32;
        fx4 s0 = (fx4){0.f,0.f,0.f,0.f}, s1 = (fx4){0.f,0.f,0.f,0.f};
        #pragma unroll
        for (int c = 0; c < 8; ++c) {
            u16x8 ka = *(const u16x8*)&Ks[lane16 * 264 + c * 32 + quad * 8];
            u16x8 kb = *(const u16x8*)&Ks[(16 + lane16) * 264 + c * 32 + quad * 8];
            s0 = mfma16(ka, qf[c], s0);
            s1 = mfma16(kb, qf[c], s1);
        }

        float p0[4], p1[4];
        int q = q0w + lane16;
        #pragma unroll
        for (int r = 0; r < 4; ++r) {
            int ka_ = k0 + quad * 4 + r;
            float e0 = exp2f(s0[r] * Cs2);
            float e1 = exp2f(s1[r] * Cs2);
            p0[r] = (ka_      <= q) ? e0 : 0.f;
            p1[r] = (ka_ + 16 <= q) ? e1 : 0.f;
            lsum += p0[r] + p1[r];
        }

        u16x8 pf;
        #pragma unroll
        for (int j = 0; j < 8; ++j) {
            int srcLane = ((((quad << 1) + (j >> 2)) & 3) << 4) | lane16;
            float v0 = __shfl(p0[j & 3], srcLane, 64);
            float v1 = __shfl(p1[j & 3], srcLane, 64);
            pf[j] = f2bf(quad >= 2 ? v1 : v0);
        }

        #pragma unroll
        for (int ft = 0; ft < 16; ++ft) {
            u16x8 vf = *(const u16x8*)&Vs[(ft * 16 + lane16) * 40 + quad * 8];
            o[ft] = mfma16(pf, vf, o[ft]);
        }
    }

    lsum += __shfl_xor(lsum, 16, 64);
    lsum += __shfl_xor(lsum, 32, 64);

    if (kc == 3) {
        float linv = 1.f / lsum;
        float inv[4];
        #pragma unroll
        for (int r = 0; r < 4; ++r) inv[r] = __shfl(linv, quad * 4 + r, 64);
        int b = bh / 3, h = bh - (bh / 3) * 3;
        unsigned short* hp = heads + (b * SEQ + q0w + quad * 4) * EMBD + h * HDIM + lane16;
        #pragma unroll
        for (int ft = 0; ft < 16; ++ft)
            #pragma unroll
            for (int r = 0; r < 4; ++r)
                hp[r * EMBD + ft * 16] = f2bf(o[ft][r] * inv[r]);
    } else {
        int slot = (bh * 16 + (qt - 16)) * 2 + kc;
        float* Op = Opart + slot * 16384 + (w * 16 + quad * 4) * 256 + lane16;
        #pragma unroll
        for (int ft = 0; ft < 16; ++ft)
            #pragma unroll
            for (int r = 0; r < 4; ++r)
                Op[r * 256 + ft * 16] = o[ft][r];
        if (quad == 0) Lpart[slot * 64 + w * 16 + lane16] = lsum;
    }
}

// ---------------------------------------------------------------------------
// Kernel 4: combine split-k partials (qt>=16), normalize, write heads bf16.
// (exact baseline revert)
// ---------------------------------------------------------------------------
__global__ __launch_bounds__(256) void combine_kernel(
    const float* __restrict__ Opart, const float* __restrict__ Lpart,
    unsigned short* __restrict__ heads)
{
    int t = blockIdx.x;              // bh*16 + (qt-16)
    int bh = t >> 4, qt = (t & 15) + 16;
    int s0 = t * 2, s1 = s0 + 1;
    int tid = threadIdx.x;
    int row = tid >> 2, fseg = (tid & 3) * 64;
    float l = Lpart[s0 * 64 + row] + Lpart[s1 * 64 + row];
    float inv = 1.f / l;
    const fx4* O0 = (const fx4*)(Opart + s0 * 16384 + row * 256 + fseg);
    const fx4* O1 = (const fx4*)(Opart + s1 * 16384 + row * 256 + fseg);
    int b = bh / 3, h = bh - (bh / 3) * 3;
    unsigned short* hp = heads + (b * SEQ + qt * 64 + row) * EMBD + h * HDIM + fseg;
    #pragma unroll
    for (int i = 0; i < 16; ++i) {
        fx4 v = O0[i] + O1[i];
        u16x4 pk;
        pk[0] = f2bf(v[0] * inv); pk[1] = f2bf(v[1] * inv);
        pk[2] = f2bf(v[2] * inv); pk[3] = f2bf(v[3] * inv);
        *(u16x4*)(hp + i * 4) = pk;
    }
}

// ---------------------------------------------------------------------------
// Kernel 5: output projection — BK=64 with the same XOR chunk swizzle as
// proj_kernel; direct fp32 stores. grid (64, 6).
// ---------------------------------------------------------------------------
__global__ __launch_bounds__(256) void outproj_kernel(
    const unsigned short* __restrict__ A, const unsigned short* __restrict__ Wot,
    const float* __restrict__ bo, float* __restrict__ out)
{
    __shared__ alignas(16) unsigned short S[16384];
    unsigned short* As = S;
    unsigned short* Bs = S + 8192;

    int m0 = blockIdx.x * 128, n0 = blockIdx.y * 128;
    int tid = threadIdx.x;
    int w = tid >> 6, ln = tid & 63;
    int lane16 = ln & 15, quad = ln >> 4;
    int mw = (w & 1) * 64, nw = (w >> 1) * 64;

    fx4 acc[4][4];
    #pragma unroll
    for (int i = 0; i < 4; ++i)
        #pragma unroll
        for (int j = 0; j < 4; ++j) acc[i][j] = (fx4){0.f, 0.f, 0.f, 0.f};

    const unsigned short *Ag[4], *Wg[4];
    #pragma unroll
    for (int i = 0; i < 4; ++i) {
        int c = tid + 256 * i;
        int R = c >> 3;
        int So = (((c & 7) ^ (R & 7)) * 8);
        Ag[i] = A + (m0 + R) * EMBD + So;
        Wg[i] = Wot + (n0 + R) * EMBD + So;
    }
    int ca0 = ((quad + 0) ^ (lane16 & 7)) * 8;
    int ca1 = ((quad + 4) ^ (lane16 & 7)) * 8;

    for (int kb = 0; kb < EMBD; kb += 64) {
        __syncthreads();
        #pragma unroll
        for (int i = 0; i < 4; ++i) {
            gl_lds16(Ag[i] + kb, &As[(tid + 256 * i) * 8]);
            gl_lds16(Wg[i] + kb, &Bs[(tid + 256 * i) * 8]);
        }
        __syncthreads();

        #pragma unroll
        for (int kh = 0; kh < 2; ++kh) {
            int co = kh ? ca1 : ca0;
            u16x8 af[4], bf[4];
            #pragma unroll
            for (int i = 0; i < 4; ++i) {
                af[i] = *(const u16x8*)&As[(mw + i * 16 + lane16) * 64 + co];
                bf[i] = *(const u16x8*)&Bs[(nw + i * 16 + lane16) * 64 + co];
            }
            #pragma unroll
            for (int i = 0; i < 4; ++i)
                #pragma unroll
                for (int j = 0; j < 4; ++j)
                    acc[i][j] = mfma16(af[i], bf[j], acc[i][j]);
        }
    }

    #pragma unroll
    for (int i = 0; i < 4; ++i) {
        int mb = m0 + mw + i * 16 + quad * 4;
        #pragma unroll
        for (int j = 0; j < 4; ++j) {
            int n = n0 + nw + j * 16 + lane16;
            float bias = bo[n];
            #pragma unroll
            for (int r = 0; r < 4; ++r)
                out[(mb + r) * EMBD + n] = acc[i][j][r] + bias;
        }
    }
}

// ---------------------------------------------------------------------------
extern "C" void kernel_launch(void* const* d_in, const int* in_sizes, int n_in,
                              void* d_out, int out_size, void* d_ws, size_t ws_size,
                              hipStream_t stream) {
    const float* Ak = (const float*)d_in[0];
    const float* Av = (const float*)d_in[1];
    const float* Aq = (const float*)d_in[2];
    const float* Wk = (const float*)d_in[3];
    const float* Wv = (const float*)d_in[4];
    const float* Wq = (const float*)d_in[5];
    const float* Wo = (const float*)d_in[6];
    const float* bo = (const float*)d_in[7];
    float* out = (float*)d_out;

    char* base = (char*)d_ws;
    unsigned short* Wt    = (unsigned short*)(base);               // 3.54 MB
    unsigned short* Wot   = (unsigned short*)(base + 3538944);     // 1.18 MB
    unsigned short* Abf   = (unsigned short*)(base + 4718592);     // 37.75 MB
    unsigned short* Kg    = (unsigned short*)(base + 42467328);    // 12.58 MB
    unsigned short* Vg    = (unsigned short*)(base + 55050240);    // 12.58 MB
    unsigned short* Qg    = (unsigned short*)(base + 67633152);    // 12.58 MB
    unsigned short* heads = (unsigned short*)(base + 80216064);    // 12.58 MB
    // split-k partials overlay the Abf region (Abf dead after proj_kernel)
    float* Opart = (float*)(base + 4718592);                       // 25.17 MB
    float* Lpart = (float*)(base + 4718592 + 25165824);            // 98 KB

    castAw_kernel<<<dim3(9792), dim3(256), 0, stream>>>(
        Ak, Av, Aq, Wk, Wv, Wq, Wo, Abf, Wt, Wot);
    proj_kernel<<<dim3(64, 6, 3), dim3(256), 0, stream>>>(
        Abf, Wt, Kg, Vg, Qg);
    attn_kernel<<<dim3(576), dim3(256), 0, stream>>>(
        Kg, Vg, Qg, heads, Opart, Lpart);
    combine_kernel<<<dim3(192), dim3(256), 0, stream>>>(Opart, Lpart, heads);
    outproj_kernel<<<dim3(64, 6), dim3(256), 0, stream>>>(heads, Wot, bo, out);
}